// Round 19
// baseline (83.491 us; speedup 1.0000x reference)
//
#include <hip/hip_runtime.h>
#include <hip/hip_fp16.h>
#include <math.h>

static constexpr int NTOK = 100000;
static constexpr int NE   = 600000;
static constexpr int NPOS = 64 * 200;   // BATCH * MAX_LEN
static constexpr int NBKT = 196;        // ceil(NTOK/512), bucket = dst >> 9
static constexpr int BCAP = 5120;       // per-bucket edge capacity (mean 3072, +37 sigma)
static constexpr int EPB  = 2344;       // edges per k_bucket block (256 blocks)
static constexpr int EPT  = 10;         // edges per thread (256*10 >= EPB)
static constexpr int NFLG = (NPOS + 255) / 256;       // flag-set blocks (50)
static constexpr int NCVT = (NTOK * 8 + 255) / 256;   // conversion blocks (3125)
static constexpr int ZERO4 = 804864 / 16;             // int4s to zero in setup

typedef unsigned long long ull;

__device__ __forceinline__ float2 h2f(unsigned int u) {
    __half2 h = *reinterpret_cast<__half2*>(&u);
    return __half22float2(h);
}
__device__ __forceinline__ unsigned int f2h(float a, float b) {
    __half2 h = __floats2half2_rn(a, b);
    return *reinterpret_cast<unsigned int*>(&h);
}
__device__ __forceinline__ float u16f(unsigned short x) {
    __half h = *reinterpret_cast<__half*>(&x);
    return __half2float(h);
}

// ---- zero bucketCnt + wl_n + flagT + flagU (one contiguous span) ----
__global__ void k_setup(int4* __restrict__ p) {
    int i = blockIdx.x * 256 + threadIdx.x;
    if (i < ZERO4) p[i] = {0, 0, 0, 0};
}

// ---- phase 1 (merged grid):
//      [0,256):   bucket-scatter edges with coalesced emission
//      [256,260): W12 = W1@W2, bw = b1@W2
//      [260,310): flagT/flagU[inp[p]] = 1
//      [310,..):  emb -> fp16 conversion ----
__global__ __launch_bounds__(256) void
k_bucket(const int* __restrict__ ei, int* __restrict__ bucketCnt,
         ull* __restrict__ buckets,
         const float4* __restrict__ W14, const float* __restrict__ b1,
         const float4* __restrict__ W24, float4* __restrict__ W124,
         float4* __restrict__ bw4,
         const int* __restrict__ inp, int* __restrict__ flagT,
         int* __restrict__ flagU,
         const float4* __restrict__ emb4, uint4* __restrict__ embh4) {
    __shared__ int cnt[256];
    __shared__ int pref[256];
    __shared__ int eoff[256];
    __shared__ int base[256];
    __shared__ ull stg[EPB];
    int t = threadIdx.x;

    if (blockIdx.x >= 260 + NFLG) {     // emb -> fp16 (one uint4 = 8 halves/thread)
        int i = (blockIdx.x - 260 - NFLG) * 256 + t;
        if (i < NTOK * 8) {
            float4 a = emb4[2 * i];
            float4 b = emb4[2 * i + 1];
            uint4 o;
            o.x = f2h(a.x, a.y); o.y = f2h(a.z, a.w);
            o.z = f2h(b.x, b.y); o.w = f2h(b.z, b.w);
            embh4[i] = o;
        }
        return;
    }
    if (blockIdx.x >= 260) {            // mark inp tokens
        int p = (blockIdx.x - 260) * 256 + t;
        if (p < NPOS) {
            int tok = inp[p];
            flagT[tok] = 1;
            flagU[tok] = 1;
        }
        return;
    }
    if (blockIdx.x >= 256) {            // W12 / bw collapse
        int blk = blockIdx.x - 256;
        int j4 = t & 15;
        int k = blk * 16 + (t >> 4);
        float4 acc = {0.f, 0.f, 0.f, 0.f};
        for (int mq = 0; mq < 32; ++mq) {
            float4 a = W14[k * 32 + mq];
            float4 w0 = W24[(4 * mq + 0) * 16 + j4];
            float4 w1 = W24[(4 * mq + 1) * 16 + j4];
            float4 w2 = W24[(4 * mq + 2) * 16 + j4];
            float4 w3 = W24[(4 * mq + 3) * 16 + j4];
            acc.x += a.x * w0.x + a.y * w1.x + a.z * w2.x + a.w * w3.x;
            acc.y += a.x * w0.y + a.y * w1.y + a.z * w2.y + a.w * w3.y;
            acc.z += a.x * w0.z + a.y * w1.z + a.z * w2.z + a.w * w3.z;
            acc.w += a.x * w0.w + a.y * w1.w + a.z * w2.w + a.w * w3.w;
        }
        W124[k * 16 + j4] = acc;
        if (blk == 0 && t < 16) {
            float4 b = {0.f, 0.f, 0.f, 0.f};
            for (int m = 0; m < 128; ++m) {
                float a = b1[m];
                float4 w = W24[m * 16 + t];
                b.x += a * w.x; b.y += a * w.y; b.z += a * w.z; b.w += a * w.w;
            }
            bw4[t] = b;
        }
        return;
    }

    // ---- bucket-scatter ----
    cnt[t] = 0;
    __syncthreads();

    int e0 = blockIdx.x * EPB;
    int eEnd = e0 + EPB; if (eEnd > NE) eEnd = NE;
    int tot = eEnd - e0;

    int s_[EPT], d_[EPT], r_[EPT];
#pragma unroll
    for (int k = 0; k < EPT; ++k) {
        int i = e0 + t + k * 256;
        s_[k] = -1;
        if (i < eEnd) {
            s_[k] = ei[i];
            d_[k] = ei[NE + i];
            r_[k] = atomicAdd(&cnt[d_[k] >> 9], 1);
        }
    }
    __syncthreads();

    int v = cnt[t];
    pref[t] = v;
    __syncthreads();
    for (int o = 1; o < 256; o <<= 1) {
        int x = pref[t];
        if (t >= o) x += pref[t - o];
        __syncthreads();
        pref[t] = x;
        __syncthreads();
    }
    eoff[t] = pref[t] - v;
    base[t] = (v > 0) ? atomicAdd(&bucketCnt[t], v) : 0;
    __syncthreads();

#pragma unroll
    for (int k = 0; k < EPT; ++k) {
        if (s_[k] >= 0) {
            int b = d_[k] >> 9;
            stg[eoff[b] + r_[k]] =
                ((ull)(unsigned)s_[k] << 32) | (unsigned)d_[k];
        }
    }
    __syncthreads();

    for (int i = t; i < tot; i += 256) {
        ull e = stg[i];
        int b = ((int)(unsigned)e) >> 9;
        int off = base[b] + (i - eoff[b]);
        if (off < BCAP) buckets[(long)b * BCAP + off] = e;
    }
}

// ---- phase 2: per-bucket CSR build (coalesced) + needU marking ----
__global__ __launch_bounds__(256) void
k_csrbuild(const ull* __restrict__ buckets, const int* __restrict__ bucketCnt,
           int* __restrict__ csr, int* __restrict__ roff, int* __restrict__ degs,
           float* __restrict__ dinv, float* __restrict__ dinv2,
           const int* __restrict__ flagT, int* __restrict__ flagU) {
    __shared__ int cnt[512];
    __shared__ int pref[512];
    __shared__ int cur[512];
    __shared__ int bsum[256];
    __shared__ int ftl[512];
    __shared__ int stg[BCAP];
    int t = threadIdx.x;
    cnt[t] = 0; cnt[t + 256] = 0;

    int b = blockIdx.x;
    int n0 = b << 9;
    {   // stage flagT for this bucket's nodes (coalesced)
        int n = n0 + t;
        ftl[t] = (n < NTOK) ? flagT[n] : 0;
        n = n0 + t + 256;
        ftl[t + 256] = (n < NTOK) ? flagT[n] : 0;
    }
    __syncthreads();

    int m = bucketCnt[b]; if (m > BCAP) m = BCAP;
    const ull* bb = buckets + (long)b * BCAP;

    for (int i = t; i < m; i += 256) {
        ull v = bb[i];
        int dd = (int)(unsigned)v;
        atomicAdd(&cnt[dd - n0], 1);
        if (ftl[dd - n0]) flagU[(int)(v >> 32)] = 1;   // mark needU src
    }
    __syncthreads();

    int a0 = cnt[2 * t], a1 = cnt[2 * t + 1];
    bsum[t] = a0 + a1;
    __syncthreads();
    for (int o = 1; o < 256; o <<= 1) {
        int x = bsum[t];
        if (t >= o) x += bsum[t - o];
        __syncthreads();
        bsum[t] = x;
        __syncthreads();
    }
    int eb = bsum[t] - (a0 + a1);
    pref[2 * t] = eb;          cur[2 * t] = eb;
    pref[2 * t + 1] = eb + a0; cur[2 * t + 1] = eb + a0;
    __syncthreads();

    for (int i = t; i < m; i += 256) {
        ull v = bb[i];
        int dd = (int)(unsigned)v;
        int ss = (int)(v >> 32);
        int pos = atomicAdd(&cur[dd - n0], 1);
        stg[pos] = ss;
    }
    __syncthreads();

    for (int i = t; i < m; i += 256) csr[(long)b * BCAP + i] = stg[i];

#pragma unroll
    for (int k = 0; k < 2; ++k) {
        int l = t + k * 256;
        int n = n0 + l;
        if (n < NTOK) {
            int dg = cnt[l];
            degs[n] = dg;
            roff[n] = b * BCAP + pref[l];
            float dd = rsqrtf((float)dg + 1.0f);
            dinv[n] = dd;
            dinv2[n] = dd * dd;
        }
    }
}

// ---- ballot-compact flagged nodes into wl (intra-wave ascending) ----
__global__ void k_compact(const int* __restrict__ flagU, int* __restrict__ wl,
                          int* __restrict__ wl_n) {
    int n = blockIdx.x * 256 + threadIdx.x;
    int lane = threadIdx.x & 63;
    int f = (n < NTOK) ? flagU[n] : 0;
    unsigned long long m = __ballot(f != 0);
    int cw = __popcll(m);
    int base = 0;
    if (lane == 0 && cw) base = atomicAdd(wl_n, cw);
    base = __builtin_amdgcn_readfirstlane(base);
    if (f) {
        int pos = base + __popcll(m & ((1ULL << lane) - 1));
        wl[pos] = n;
    }
}

// ---- pass A (fp16, worklist-gated, 8 nodes/wave, uint4 16B/lane) ----
__global__ void k_gatherA(const int* __restrict__ wl, const int* __restrict__ wl_n,
                          const int* __restrict__ csr, const int* __restrict__ roff,
                          const int* __restrict__ degs,
                          const float* __restrict__ dinv, const uint4* __restrict__ eh4,
                          uint4* __restrict__ u4, float* __restrict__ s_raw) {
    int idx = blockIdx.x * 256 + threadIdx.x;
    int wi = idx >> 3;
    if (wi >= wl_n[0]) return;
    int n = wl[wi];
    int jq = idx & 7;
    int d = degs[n];
    const int* row = csr + roff[n];

    float a[8];
    float cn = dinv[n];
    {
        uint4 v = eh4[((long)n << 3) + jq];
        float2 f0 = h2f(v.x), f1 = h2f(v.y), f2 = h2f(v.z), f3 = h2f(v.w);
        a[0] = cn * f0.x; a[1] = cn * f0.y; a[2] = cn * f1.x; a[3] = cn * f1.y;
        a[4] = cn * f2.x; a[5] = cn * f2.y; a[6] = cn * f3.x; a[7] = cn * f3.y;
    }
    float sdv = cn;
    int e = 0;
    for (; e + 4 <= d; e += 4) {
        int s0 = row[e], s1 = row[e + 1], s2 = row[e + 2], s3 = row[e + 3];
        float c0 = dinv[s0], c1 = dinv[s1], c2 = dinv[s2], c3 = dinv[s3];
        uint4 v0 = eh4[((long)s0 << 3) + jq];
        uint4 v1 = eh4[((long)s1 << 3) + jq];
        uint4 v2 = eh4[((long)s2 << 3) + jq];
        uint4 v3 = eh4[((long)s3 << 3) + jq];
        {
            float2 f0 = h2f(v0.x), f1 = h2f(v0.y), f2 = h2f(v0.z), f3 = h2f(v0.w);
            a[0] += c0 * f0.x; a[1] += c0 * f0.y; a[2] += c0 * f1.x; a[3] += c0 * f1.y;
            a[4] += c0 * f2.x; a[5] += c0 * f2.y; a[6] += c0 * f3.x; a[7] += c0 * f3.y;
        }
        {
            float2 f0 = h2f(v1.x), f1 = h2f(v1.y), f2 = h2f(v1.z), f3 = h2f(v1.w);
            a[0] += c1 * f0.x; a[1] += c1 * f0.y; a[2] += c1 * f1.x; a[3] += c1 * f1.y;
            a[4] += c1 * f2.x; a[5] += c1 * f2.y; a[6] += c1 * f3.x; a[7] += c1 * f3.y;
        }
        {
            float2 f0 = h2f(v2.x), f1 = h2f(v2.y), f2 = h2f(v2.z), f3 = h2f(v2.w);
            a[0] += c2 * f0.x; a[1] += c2 * f0.y; a[2] += c2 * f1.x; a[3] += c2 * f1.y;
            a[4] += c2 * f2.x; a[5] += c2 * f2.y; a[6] += c2 * f3.x; a[7] += c2 * f3.y;
        }
        {
            float2 f0 = h2f(v3.x), f1 = h2f(v3.y), f2 = h2f(v3.z), f3 = h2f(v3.w);
            a[0] += c3 * f0.x; a[1] += c3 * f0.y; a[2] += c3 * f1.x; a[3] += c3 * f1.y;
            a[4] += c3 * f2.x; a[5] += c3 * f2.y; a[6] += c3 * f3.x; a[7] += c3 * f3.y;
        }
        sdv += (c0 + c1) + (c2 + c3);
    }
    for (; e < d; ++e) {
        int sx = row[e];
        float c = dinv[sx];
        uint4 v = eh4[((long)sx << 3) + jq];
        float2 f0 = h2f(v.x), f1 = h2f(v.y), f2 = h2f(v.z), f3 = h2f(v.w);
        a[0] += c * f0.x; a[1] += c * f0.y; a[2] += c * f1.x; a[3] += c * f1.y;
        a[4] += c * f2.x; a[5] += c * f2.y; a[6] += c * f3.x; a[7] += c * f3.y;
        sdv += c;
    }
    uint4 o;
    o.x = f2h(a[0], a[1]); o.y = f2h(a[2], a[3]);
    o.z = f2h(a[4], a[5]); o.w = f2h(a[6], a[7]);
    u4[((long)n << 3) + jq] = o;
    if (jq == 0) s_raw[n] = sdv;
}

// ---- fused pass B + 64x64 matvec + biases, one position per wave ----
__global__ __launch_bounds__(256) void
k_fused(const int* __restrict__ inp, const int* __restrict__ csr,
        const int* __restrict__ roff, const int* __restrict__ degs,
        const float* __restrict__ dinv, const float* __restrict__ dinv2,
        const float* __restrict__ s_raw, const unsigned short* __restrict__ uh,
        const float* __restrict__ W12, const float* __restrict__ bw,
        const float* __restrict__ b2, float* __restrict__ out) {
    __shared__ float w[64 * 64];    // 16KB
    int tid = threadIdx.x;
    {
        const float4* W4 = (const float4*)W12;
        float4* w4 = (float4*)w;
        for (int i = tid; i < 1024; i += 256) w4[i] = W4[i];
    }
    __syncthreads();

    int lane = tid & 63;
    int wid  = tid >> 6;
    int p = blockIdx.x * 4 + wid;
    int t = inp[p];                       // wave-uniform
    int d = degs[t];
    const int* row = csr + roff[t];

    float z = dinv2[t] * u16f(uh[((long)t << 6) + lane]);
    int e = 0;
    for (; e + 4 <= d; e += 4) {
        int s0 = row[e], s1 = row[e + 1], s2 = row[e + 2], s3 = row[e + 3];
        float c0 = dinv2[s0], c1 = dinv2[s1], c2 = dinv2[s2], c3 = dinv2[s3];
        float u0 = u16f(uh[((long)s0 << 6) + lane]);
        float u1 = u16f(uh[((long)s1 << 6) + lane]);
        float u2 = u16f(uh[((long)s2 << 6) + lane]);
        float u3 = u16f(uh[((long)s3 << 6) + lane]);
        z += (c0 * u0 + c1 * u1) + (c2 * u2 + c3 * u3);
    }
    for (; e < d; ++e) {
        int sx = row[e];
        z += dinv2[sx] * u16f(uh[((long)sx << 6) + lane]);
    }
    z *= dinv[t];

    float o0 = 0.f, o1 = 0.f, o2 = 0.f, o3 = 0.f;
#pragma unroll
    for (int k = 0; k < 64; k += 4) {
        float z0 = __uint_as_float(__builtin_amdgcn_readlane(__float_as_uint(z), k));
        float z1 = __uint_as_float(__builtin_amdgcn_readlane(__float_as_uint(z), k + 1));
        float z2 = __uint_as_float(__builtin_amdgcn_readlane(__float_as_uint(z), k + 2));
        float z3 = __uint_as_float(__builtin_amdgcn_readlane(__float_as_uint(z), k + 3));
        o0 += z0 * w[(k + 0) * 64 + lane];
        o1 += z1 * w[(k + 1) * 64 + lane];
        o2 += z2 * w[(k + 2) * 64 + lane];
        o3 += z3 * w[(k + 3) * 64 + lane];
    }
    float o = (o0 + o1) + (o2 + o3) + dinv[t] * s_raw[t] * bw[lane] + b2[lane];
    out[((long)p << 6) + lane] = o;
}

extern "C" void kernel_launch(void* const* d_in, const int* in_sizes, int n_in,
                              void* d_out, int out_size, void* d_ws, size_t ws_size,
                              hipStream_t stream) {
    const int*   inp = (const int*)d_in[0];
    const float* emb = (const float*)d_in[1];
    const float* W1  = (const float*)d_in[2];
    const float* b1  = (const float*)d_in[3];
    const float* W2  = (const float*)d_in[4];
    const float* b2  = (const float*)d_in[5];
    const int*   ei  = (const int*)d_in[6];   // [2, NE]: row0 = src, row1 = dst
    float* out = (float*)d_out;

    char* ws = (char*)d_ws;
    // zero span [0, 804864): bucketCnt, wl_n, flagT, flagU
    int*   bucketCnt = (int*)(ws + 0);                 // 1 KB
    int*   wl_n  = (int*)(ws + 1024);                  // 16 B
    int*   flagT = (int*)(ws + 4096);                  // 400 KB
    int*   flagU = (int*)(ws + 404096);                // 400 KB
    float* W12   = (float*)(ws + 804864);              // 16 KB
    float* bw    = (float*)(ws + 821248);              // 256 B
    int*   degs  = (int*)(ws + 821504);                // 400 KB
    float* dinv  = (float*)(ws + 1221504);             // 400 KB
    float* dinv2 = (float*)(ws + 1621504);             // 400 KB
    float* s_raw = (float*)(ws + 2021504);             // 400 KB
    int*   roff  = (int*)(ws + 2421504);               // 400 KB
    int*   wl    = (int*)(ws + 2821504);               // 400 KB
    ull*   buckets = (ull*)(ws + 3221504);             // 8.03 MB
    int*   csr   = (int*)(ws + 11249664);              // 4.01 MB
    unsigned short* embh = (unsigned short*)(ws + 15263744); // fp16 [NTOK][64] 12.8 MB
    unsigned short* u    = (unsigned short*)(ws + 28063744); // fp16 [NTOK][64] 12.8 MB

    // ---- zero counters + flags ----
    k_setup<<<(ZERO4 + 255) / 256, 256, 0, stream>>>((int4*)ws);

    // ---- phase 1: bucket-scatter ∥ W12/bw ∥ inp-flags ∥ emb->fp16 ----
    k_bucket<<<260 + NFLG + NCVT, 256, 0, stream>>>(
        ei, bucketCnt, buckets,
        (const float4*)W1, b1, (const float4*)W2, (float4*)W12, (float4*)bw,
        inp, flagT, flagU, (const float4*)emb, (uint4*)embh);

    // ---- phase 2: CSR build + degrees + dinv + needU marking ----
    k_csrbuild<<<NBKT, 256, 0, stream>>>(buckets, bucketCnt, csr, roff,
                                         degs, dinv, dinv2, flagT, flagU);

    // ---- compact worklist ----
    k_compact<<<(NTOK + 255) / 256, 256, 0, stream>>>(flagU, wl, wl_n);

    // ---- pass A (fp16) over worklist ----
    int gblk = (NTOK * 8 + 255) / 256;
    k_gatherA<<<gblk, 256, 0, stream>>>(wl, wl_n, csr, roff, degs, dinv,
                                        (const uint4*)embh, (uint4*)u, s_raw);

    // ---- fused pass B + matvec + biases ----
    k_fused<<<NPOS / 4, 256, 0, stream>>>(inp, csr, roff, degs, dinv, dinv2,
                                          s_raw, u, W12, bw, b2, out);
}

// Round 20
// 66.947 us; speedup vs baseline: 1.2471x; 1.2471x over previous
//
#include <hip/hip_runtime.h>
#include <hip/hip_fp16.h>
#include <math.h>

static constexpr int NTOK = 100000;
static constexpr int NE   = 600000;
static constexpr int NPOS = 64 * 200;   // BATCH * MAX_LEN
static constexpr int NBKT = 196;        // ceil(NTOK/512), bucket = dst >> 9
static constexpr int BCAP = 5120;       // per-bucket edge capacity (mean 3072, +37 sigma)
static constexpr int EPB  = 2344;       // edges per k_bucket block (256 blocks)
static constexpr int EPT  = 10;         // edges per thread (256*10 >= EPB)
static constexpr int NCVT = (NTOK * 8 + 255) / 256;   // conversion blocks (3125)

typedef unsigned long long ull;

__device__ __forceinline__ float2 h2f(unsigned int u) {
    __half2 h = *reinterpret_cast<__half2*>(&u);
    return __half22float2(h);
}
__device__ __forceinline__ unsigned int f2h(float a, float b) {
    __half2 h = __floats2half2_rn(a, b);
    return *reinterpret_cast<unsigned int*>(&h);
}
__device__ __forceinline__ float u16f(unsigned short x) {
    __half h = *reinterpret_cast<__half*>(&x);
    return __half2float(h);
}

// ---- tiny: zero bucket counters ----
__global__ void k_setup(int* __restrict__ bucketCnt) {
    bucketCnt[threadIdx.x] = 0;     // 256 >= NBKT
}

// ---- phase 1 (merged grid):
//      blocks [0,256): bucket-scatter edges with coalesced emission
//      blocks [256,260): W12 = W1@W2, bw = b1@W2
//      blocks [260,..): emb -> fp16 conversion (needed only by gatherA) ----
__global__ __launch_bounds__(256) void
k_bucket(const int* __restrict__ ei, int* __restrict__ bucketCnt,
         ull* __restrict__ buckets,
         const float4* __restrict__ W14, const float* __restrict__ b1,
         const float4* __restrict__ W24, float4* __restrict__ W124,
         float4* __restrict__ bw4,
         const float4* __restrict__ emb4, uint4* __restrict__ embh4) {
    __shared__ int cnt[256];
    __shared__ int pref[256];
    __shared__ int eoff[256];
    __shared__ int base[256];
    __shared__ ull stg[EPB];
    int t = threadIdx.x;

    if (blockIdx.x >= 260) {            // emb -> fp16 (one uint4 = 8 halves/thread)
        int i = (blockIdx.x - 260) * 256 + t;
        if (i < NTOK * 8) {
            float4 a = emb4[2 * i];
            float4 b = emb4[2 * i + 1];
            uint4 o;
            o.x = f2h(a.x, a.y); o.y = f2h(a.z, a.w);
            o.z = f2h(b.x, b.y); o.w = f2h(b.z, b.w);
            embh4[i] = o;
        }
        return;
    }
    if (blockIdx.x >= 256) {            // W12 / bw collapse
        int blk = blockIdx.x - 256;
        int j4 = t & 15;
        int k = blk * 16 + (t >> 4);
        float4 acc = {0.f, 0.f, 0.f, 0.f};
        for (int mq = 0; mq < 32; ++mq) {
            float4 a = W14[k * 32 + mq];
            float4 w0 = W24[(4 * mq + 0) * 16 + j4];
            float4 w1 = W24[(4 * mq + 1) * 16 + j4];
            float4 w2 = W24[(4 * mq + 2) * 16 + j4];
            float4 w3 = W24[(4 * mq + 3) * 16 + j4];
            acc.x += a.x * w0.x + a.y * w1.x + a.z * w2.x + a.w * w3.x;
            acc.y += a.x * w0.y + a.y * w1.y + a.z * w2.y + a.w * w3.y;
            acc.z += a.x * w0.z + a.y * w1.z + a.z * w2.z + a.w * w3.z;
            acc.w += a.x * w0.w + a.y * w1.w + a.z * w2.w + a.w * w3.w;
        }
        W124[k * 16 + j4] = acc;
        if (blk == 0 && t < 16) {
            float4 b = {0.f, 0.f, 0.f, 0.f};
            for (int m = 0; m < 128; ++m) {
                float a = b1[m];
                float4 w = W24[m * 16 + t];
                b.x += a * w.x; b.y += a * w.y; b.z += a * w.z; b.w += a * w.w;
            }
            bw4[t] = b;
        }
        return;
    }

    // ---- bucket-scatter ----
    cnt[t] = 0;
    __syncthreads();

    int e0 = blockIdx.x * EPB;
    int eEnd = e0 + EPB; if (eEnd > NE) eEnd = NE;
    int tot = eEnd - e0;

    int s_[EPT], d_[EPT], r_[EPT];
#pragma unroll
    for (int k = 0; k < EPT; ++k) {
        int i = e0 + t + k * 256;
        s_[k] = -1;
        if (i < eEnd) {
            s_[k] = ei[i];
            d_[k] = ei[NE + i];
            r_[k] = atomicAdd(&cnt[d_[k] >> 9], 1);
        }
    }
    __syncthreads();

    int v = cnt[t];
    pref[t] = v;
    __syncthreads();
    for (int o = 1; o < 256; o <<= 1) {
        int x = pref[t];
        if (t >= o) x += pref[t - o];
        __syncthreads();
        pref[t] = x;
        __syncthreads();
    }
    eoff[t] = pref[t] - v;
    base[t] = (v > 0) ? atomicAdd(&bucketCnt[t], v) : 0;
    __syncthreads();

#pragma unroll
    for (int k = 0; k < EPT; ++k) {
        if (s_[k] >= 0) {
            int b = d_[k] >> 9;
            stg[eoff[b] + r_[k]] =
                ((ull)(unsigned)s_[k] << 32) | (unsigned)d_[k];
        }
    }
    __syncthreads();

    for (int i = t; i < tot; i += 256) {
        ull e = stg[i];
        int b = ((int)(unsigned)e) >> 9;
        int off = base[b] + (i - eoff[b]);
        if (off < BCAP) buckets[(long)b * BCAP + off] = e;
    }
}

// ---- phase 2: per-bucket CSR build, all global writes coalesced ----
__global__ __launch_bounds__(256) void
k_csrbuild(const ull* __restrict__ buckets, const int* __restrict__ bucketCnt,
           int* __restrict__ csr, int* __restrict__ roff, int* __restrict__ degs,
           float* __restrict__ dinv, float* __restrict__ dinv2) {
    __shared__ int cnt[512];
    __shared__ int pref[512];
    __shared__ int cur[512];
    __shared__ int bsum[256];
    __shared__ int stg[BCAP];
    int t = threadIdx.x;
    cnt[t] = 0; cnt[t + 256] = 0;
    __syncthreads();

    int b = blockIdx.x;
    int n0 = b << 9;
    int m = bucketCnt[b]; if (m > BCAP) m = BCAP;
    const ull* bb = buckets + (long)b * BCAP;

    for (int i = t; i < m; i += 256) {
        int dd = (int)(unsigned)bb[i];
        atomicAdd(&cnt[dd - n0], 1);
    }
    __syncthreads();

    int a0 = cnt[2 * t], a1 = cnt[2 * t + 1];
    bsum[t] = a0 + a1;
    __syncthreads();
    for (int o = 1; o < 256; o <<= 1) {
        int x = bsum[t];
        if (t >= o) x += bsum[t - o];
        __syncthreads();
        bsum[t] = x;
        __syncthreads();
    }
    int eb = bsum[t] - (a0 + a1);
    pref[2 * t] = eb;          cur[2 * t] = eb;
    pref[2 * t + 1] = eb + a0; cur[2 * t + 1] = eb + a0;
    __syncthreads();

    for (int i = t; i < m; i += 256) {
        ull v = bb[i];
        int dd = (int)(unsigned)v;
        int ss = (int)(v >> 32);
        int pos = atomicAdd(&cur[dd - n0], 1);
        stg[pos] = ss;
    }
    __syncthreads();

    for (int i = t; i < m; i += 256) csr[(long)b * BCAP + i] = stg[i];

#pragma unroll
    for (int k = 0; k < 2; ++k) {
        int l = t + k * 256;
        int n = n0 + l;
        if (n < NTOK) {
            int dg = cnt[l];
            degs[n] = dg;
            roff[n] = b * BCAP + pref[l];
            float dd = rsqrtf((float)dg + 1.0f);
            dinv[n] = dd;
            dinv2[n] = dd * dd;
        }
    }
}

// ---- pass A (fp16): u[n] = dinv[n]*embh[n] + sum_src dinv[src]*embh[src];
//      8 lanes per node (8 halves/lane); s_raw via jq==0 ----
__global__ void k_gatherA(const int* __restrict__ csr, const int* __restrict__ roff,
                          const int* __restrict__ degs,
                          const float* __restrict__ dinv, const uint4* __restrict__ eh4,
                          uint4* __restrict__ u4, float* __restrict__ s_raw) {
    int idx = blockIdx.x * 256 + threadIdx.x;
    int n = idx >> 3;
    if (n >= NTOK) return;
    int jq = idx & 7;
    int d = degs[n];
    const int* row = csr + roff[n];

    float a[8];
    float cn = dinv[n];
    {
        uint4 v = eh4[((long)n << 3) + jq];
        float2 f0 = h2f(v.x), f1 = h2f(v.y), f2 = h2f(v.z), f3 = h2f(v.w);
        a[0] = cn * f0.x; a[1] = cn * f0.y; a[2] = cn * f1.x; a[3] = cn * f1.y;
        a[4] = cn * f2.x; a[5] = cn * f2.y; a[6] = cn * f3.x; a[7] = cn * f3.y;
    }
    float sdv = cn;
    int e = 0;
    for (; e + 4 <= d; e += 4) {
        int s0 = row[e], s1 = row[e + 1], s2 = row[e + 2], s3 = row[e + 3];
        float c0 = dinv[s0], c1 = dinv[s1], c2 = dinv[s2], c3 = dinv[s3];
        uint4 v0 = eh4[((long)s0 << 3) + jq];
        uint4 v1 = eh4[((long)s1 << 3) + jq];
        uint4 v2 = eh4[((long)s2 << 3) + jq];
        uint4 v3 = eh4[((long)s3 << 3) + jq];
        {
            float2 f0 = h2f(v0.x), f1 = h2f(v0.y), f2 = h2f(v0.z), f3 = h2f(v0.w);
            a[0] += c0 * f0.x; a[1] += c0 * f0.y; a[2] += c0 * f1.x; a[3] += c0 * f1.y;
            a[4] += c0 * f2.x; a[5] += c0 * f2.y; a[6] += c0 * f3.x; a[7] += c0 * f3.y;
        }
        {
            float2 f0 = h2f(v1.x), f1 = h2f(v1.y), f2 = h2f(v1.z), f3 = h2f(v1.w);
            a[0] += c1 * f0.x; a[1] += c1 * f0.y; a[2] += c1 * f1.x; a[3] += c1 * f1.y;
            a[4] += c1 * f2.x; a[5] += c1 * f2.y; a[6] += c1 * f3.x; a[7] += c1 * f3.y;
        }
        {
            float2 f0 = h2f(v2.x), f1 = h2f(v2.y), f2 = h2f(v2.z), f3 = h2f(v2.w);
            a[0] += c2 * f0.x; a[1] += c2 * f0.y; a[2] += c2 * f1.x; a[3] += c2 * f1.y;
            a[4] += c2 * f2.x; a[5] += c2 * f2.y; a[6] += c2 * f3.x; a[7] += c2 * f3.y;
        }
        {
            float2 f0 = h2f(v3.x), f1 = h2f(v3.y), f2 = h2f(v3.z), f3 = h2f(v3.w);
            a[0] += c3 * f0.x; a[1] += c3 * f0.y; a[2] += c3 * f1.x; a[3] += c3 * f1.y;
            a[4] += c3 * f2.x; a[5] += c3 * f2.y; a[6] += c3 * f3.x; a[7] += c3 * f3.y;
        }
        sdv += (c0 + c1) + (c2 + c3);
    }
    for (; e < d; ++e) {
        int sx = row[e];
        float c = dinv[sx];
        uint4 v = eh4[((long)sx << 3) + jq];
        float2 f0 = h2f(v.x), f1 = h2f(v.y), f2 = h2f(v.z), f3 = h2f(v.w);
        a[0] += c * f0.x; a[1] += c * f0.y; a[2] += c * f1.x; a[3] += c * f1.y;
        a[4] += c * f2.x; a[5] += c * f2.y; a[6] += c * f3.x; a[7] += c * f3.y;
        sdv += c;
    }
    uint4 o;
    o.x = f2h(a[0], a[1]); o.y = f2h(a[2], a[3]);
    o.z = f2h(a[4], a[5]); o.w = f2h(a[6], a[7]);
    u4[((long)n << 3) + jq] = o;
    if (jq == 0) s_raw[n] = sdv;
}

// ---- fused pass B + 64x64 matvec + biases, one position per wave ----
__global__ __launch_bounds__(256) void
k_fused(const int* __restrict__ inp, const int* __restrict__ csr,
        const int* __restrict__ roff, const int* __restrict__ degs,
        const float* __restrict__ dinv, const float* __restrict__ dinv2,
        const float* __restrict__ s_raw, const unsigned short* __restrict__ uh,
        const float* __restrict__ W12, const float* __restrict__ bw,
        const float* __restrict__ b2, float* __restrict__ out) {
    __shared__ float w[64 * 64];    // 16KB
    int tid = threadIdx.x;
    {
        const float4* W4 = (const float4*)W12;
        float4* w4 = (float4*)w;
        for (int i = tid; i < 1024; i += 256) w4[i] = W4[i];
    }
    __syncthreads();

    int lane = tid & 63;
    int wid  = tid >> 6;
    int p = blockIdx.x * 4 + wid;
    int t = inp[p];                       // wave-uniform
    int d = degs[t];
    const int* row = csr + roff[t];

    float z = dinv2[t] * u16f(uh[((long)t << 6) + lane]);
    int e = 0;
    for (; e + 4 <= d; e += 4) {
        int s0 = row[e], s1 = row[e + 1], s2 = row[e + 2], s3 = row[e + 3];
        float c0 = dinv2[s0], c1 = dinv2[s1], c2 = dinv2[s2], c3 = dinv2[s3];
        float u0 = u16f(uh[((long)s0 << 6) + lane]);
        float u1 = u16f(uh[((long)s1 << 6) + lane]);
        float u2 = u16f(uh[((long)s2 << 6) + lane]);
        float u3 = u16f(uh[((long)s3 << 6) + lane]);
        z += (c0 * u0 + c1 * u1) + (c2 * u2 + c3 * u3);
    }
    for (; e < d; ++e) {
        int sx = row[e];
        z += dinv2[sx] * u16f(uh[((long)sx << 6) + lane]);
    }
    z *= dinv[t];

    float o0 = 0.f, o1 = 0.f, o2 = 0.f, o3 = 0.f;
#pragma unroll
    for (int k = 0; k < 64; k += 4) {
        float z0 = __uint_as_float(__builtin_amdgcn_readlane(__float_as_uint(z), k));
        float z1 = __uint_as_float(__builtin_amdgcn_readlane(__float_as_uint(z), k + 1));
        float z2 = __uint_as_float(__builtin_amdgcn_readlane(__float_as_uint(z), k + 2));
        float z3 = __uint_as_float(__builtin_amdgcn_readlane(__float_as_uint(z), k + 3));
        o0 += z0 * w[(k + 0) * 64 + lane];
        o1 += z1 * w[(k + 1) * 64 + lane];
        o2 += z2 * w[(k + 2) * 64 + lane];
        o3 += z3 * w[(k + 3) * 64 + lane];
    }
    float o = (o0 + o1) + (o2 + o3) + dinv[t] * s_raw[t] * bw[lane] + b2[lane];
    out[((long)p << 6) + lane] = o;
}

extern "C" void kernel_launch(void* const* d_in, const int* in_sizes, int n_in,
                              void* d_out, int out_size, void* d_ws, size_t ws_size,
                              hipStream_t stream) {
    const int*   inp = (const int*)d_in[0];
    const float* emb = (const float*)d_in[1];
    const float* W1  = (const float*)d_in[2];
    const float* b1  = (const float*)d_in[3];
    const float* W2  = (const float*)d_in[4];
    const float* b2  = (const float*)d_in[5];
    const int*   ei  = (const int*)d_in[6];   // [2, NE]: row0 = src, row1 = dst
    float* out = (float*)d_out;

    char* ws = (char*)d_ws;
    int*   bucketCnt = (int*)(ws + 0);                 // 1 KB
    float* W12   = (float*)(ws + 4096);                // 16 KB
    float* bw    = (float*)(ws + 20480);               // 256 B
    int*   degs  = (int*)(ws + 24576);                 // 400 KB
    float* dinv  = (float*)(ws + 424576);              // 400 KB
    float* dinv2 = (float*)(ws + 824576);              // 400 KB
    float* s_raw = (float*)(ws + 1224576);             // 400 KB
    int*   roff  = (int*)(ws + 1624576);               // 400 KB
    ull*   buckets = (ull*)(ws + 2024576);             // 8.03 MB
    int*   csr   = (int*)(ws + 10052736);              // 4.01 MB
    unsigned short* embh = (unsigned short*)(ws + 14066816); // fp16 [NTOK][64] 12.8 MB
    unsigned short* u    = (unsigned short*)(ws + 26866816); // fp16 [NTOK][64] 12.8 MB

    // ---- zero bucket counters (tiny) ----
    k_setup<<<1, 256, 0, stream>>>(bucketCnt);

    // ---- phase 1: bucket-scatter ∥ W12/bw ∥ emb->fp16 (one grid) ----
    k_bucket<<<260 + NCVT, 256, 0, stream>>>(
        ei, bucketCnt, buckets,
        (const float4*)W1, b1, (const float4*)W2, (float4*)W12, (float4*)bw,
        (const float4*)emb, (uint4*)embh);

    // ---- phase 2: per-bucket CSR build + degrees + dinv ----
    k_csrbuild<<<NBKT, 256, 0, stream>>>(buckets, bucketCnt, csr, roff,
                                         degs, dinv, dinv2);

    // ---- pass A (fp16) over all nodes ----
    int gblk = (NTOK * 8 + 255) / 256;
    k_gatherA<<<gblk, 256, 0, stream>>>(csr, roff, degs, dinv, (const uint4*)embh,
                                        (uint4*)u, s_raw);

    // ---- fused pass B + matvec + biases ----
    k_fused<<<NPOS / 4, 256, 0, stream>>>(inp, csr, roff, degs, dinv, dinv2,
                                          s_raw, u, W12, bw, b2, out);
}